// Round 1
// 508.864 us; speedup vs baseline: 1.0119x; 1.0119x over previous
//
#include <hip/hip_runtime.h>
#include <cstdint>

// R6: 256x256-tile, 512-thread (8-wave 2x4) GEMM with BK=32 4-slot LDS ring
// (128KB), counted s_waitcnt vmcnt(8) per slot (T3+T4), setprio around the
// MFMA cluster (T5), chunk-XOR-swizzled LDS kept conflict-free with linear
// global_load_lds staging (pre-swizzled global source). One barrier + one
// counted vmcnt per BK=32 slot; prefetch distance = 3 slots (~HBM latency).
// Tail peels with vmcnt(4)/vmcnt(0). STATS epilogue reworked for 8x4 frags
// (gn=4 partials; softmax_apply combine 8->4).

#define L2E 1.4426950408889634f

typedef _Float16 half8 __attribute__((ext_vector_type(8)));
typedef _Float16 half4v __attribute__((ext_vector_type(4)));
typedef float f32x4 __attribute__((ext_vector_type(4)));

__device__ __forceinline__ void gl_lds16(const void* g, void* l) {
  __builtin_amdgcn_global_load_lds(
      (const __attribute__((address_space(1))) unsigned int*)g,
      (__attribute__((address_space(3))) unsigned int*)l, 16, 0, 0);
}

// C(M,N) = op( X(M,K) @ Y(N,K)^T + bias ), op = relu if BIASRELU.
// 1D grid + XCD swizzle (id&7 -> XCD). shalf>0: merged two-gemm launch.
// STATS: emit row/col softmax partials (gn=4 layout).
template<int K, bool BIASRELU, bool STATS, typename OutT>
__global__ __launch_bounds__(512, 2)
void gemm_k(const _Float16* __restrict__ X, const _Float16* __restrict__ Y,
            const float* __restrict__ bias, OutT* __restrict__ C, int N,
            long xbs, long ybs, long cbs, int gm, int gn, int gz,
            float* __restrict__ prm, float* __restrict__ prs,
            float* __restrict__ pcm, float* __restrict__ pcs,
            const _Float16* __restrict__ X2, const _Float16* __restrict__ Y2,
            OutT* __restrict__ C2, int shalf)
{
  constexpr int NS = K / 32;                 // BK=32 slots
  __shared__ __align__(16) _Float16 sm[65536];  // 4 slots x (8192 A + 8192 B)
  const int t = threadIdx.x;
  const int lane = t & 63, w = t >> 6;       // 8 waves
  const int wr = w >> 2, wc = w & 3;         // 2 x 4 wave grid
  const int lm = lane & 15, g = lane >> 4;

  // block decode
  const int id = blockIdx.x;
  const int c = id & 7;
  int s0 = id >> 3;
  if (shalf && s0 >= shalf) { s0 -= shalf; X = X2; Y = Y2; C = C2; }
  int m, n, bz;
  if (gz == 1) {
    int q = s0 / gn;
    n = s0 - q * gn;
    m = c * (gm >> 3) + q;
    bz = 0;
  } else {
    int tpb = gm * gn;
    int bq = s0 / tpb;
    bz = c * (gz >> 3) + bq;
    int r = s0 - bq * tpb;
    m = r / gn;
    n = r - m * gn;
  }
  const int m0 = m * 256, n0 = n * 256;

  X += (size_t)bz * xbs;
  Y += (size_t)bz * ybs;
  C += (size_t)bz * cbs;

  // Staging descriptors. LDS 16B chunk ci = j*512 + t (linear in lane order,
  // as global_load_lds requires). Inverse swizzle to find the global source:
  // phys (lr, p) -> logical chunk cc = p ^ (lr&7); row r = 2*lr + (cc>>2);
  // k-chunk = cc&3.
  const _Float16* ag[2]; const _Float16* bg[2];
  _Float16* al[2]; _Float16* bl[2];
#pragma unroll
  for (int j = 0; j < 2; ++j) {
    int ci = j * 512 + t;
    int lr = ci >> 3, p = ci & 7;
    int cc = p ^ (lr & 7);
    int r = lr * 2 + (cc >> 2);
    int kb = (cc & 3) * 8;
    ag[j] = X + (size_t)(m0 + r) * K + kb;
    bg[j] = Y + (size_t)(n0 + r) * K + kb;
    al[j] = sm + ci * 8;
    bl[j] = sm + 8192 + ci * 8;
  }

  // Fragment LDS offsets (f16 units): logical row r, k-chunk g ->
  // lr = r>>1, chunk = ((r&1)*4 + g) ^ (lr&7).
  int aoff[8], boff[4];
#pragma unroll
  for (int mi = 0; mi < 8; ++mi) {
    int r = wr * 128 + mi * 16 + lm;
    int lr = r >> 1;
    aoff[mi] = lr * 64 + ((((lm & 1) << 2) + g) ^ (lr & 7)) * 8;
  }
#pragma unroll
  for (int ni = 0; ni < 4; ++ni) {
    int r = wc * 64 + ni * 16 + lm;
    int lr = r >> 1;
    boff[ni] = lr * 64 + ((((lm & 1) << 2) + g) ^ (lr & 7)) * 8;
  }

  f32x4 acc[8][4] = {};

#define STAGE_(ss) { \
    const int sb_ = ((ss) & 3) * 16384; \
    const int kt_ = (ss) * 32; \
    gl_lds16(ag[0] + kt_, al[0] + sb_); \
    gl_lds16(ag[1] + kt_, al[1] + sb_); \
    gl_lds16(bg[0] + kt_, bl[0] + sb_); \
    gl_lds16(bg[1] + kt_, bl[1] + sb_); }

  // One barrier + one counted vmcnt per slot. Stage for slot ss+3 targets
  // ring[(ss-1)&3], fully read before the barrier that opened slot ss.
#define SLOT_(ss, VM) { \
    asm volatile("s_waitcnt vmcnt(" #VM ")" ::: "memory"); \
    __builtin_amdgcn_s_barrier(); \
    const _Float16* ab_ = sm + ((ss) & 3) * 16384; \
    const _Float16* bb_ = ab_ + 8192; \
    half8 af[8]; half8 bf[4]; \
    _Pragma("unroll") \
    for (int mi = 0; mi < 8; ++mi) af[mi] = *(const half8*)(ab_ + aoff[mi]); \
    _Pragma("unroll") \
    for (int ni = 0; ni < 4; ++ni) bf[ni] = *(const half8*)(bb_ + boff[ni]); \
    if ((ss) + 3 < NS) STAGE_((ss) + 3); \
    __builtin_amdgcn_s_setprio(1); \
    _Pragma("unroll") \
    for (int mi = 0; mi < 8; ++mi) \
      _Pragma("unroll") \
      for (int ni = 0; ni < 4; ++ni) \
        acc[mi][ni] = __builtin_amdgcn_mfma_f32_16x16x32_f16(af[mi], bf[ni], acc[mi][ni], 0, 0, 0); \
    __builtin_amdgcn_s_setprio(0); }

  STAGE_(0); STAGE_(1); STAGE_(2);
  for (int ss = 0; ss < NS - 2; ++ss) SLOT_(ss, 8);
  SLOT_(NS - 2, 4);
  SLOT_(NS - 1, 0);
#undef STAGE_
#undef SLOT_

  // epilogue: C/D layout col = lane&15, row = (lane>>4)*4 + q
#pragma unroll
  for (int mi = 0; mi < 8; ++mi) {
    const int rb = m0 + wr * 128 + mi * 16 + g * 4;
#pragma unroll
    for (int ni = 0; ni < 4; ++ni) {
      const int col = n0 + wc * 64 + ni * 16 + lm;
      float bv = 0.f;
      if constexpr (BIASRELU) bv = bias[col];
#pragma unroll
      for (int q = 0; q < 4; ++q) {
        float v = acc[mi][ni][q] + bv;
        if constexpr (BIASRELU) v = fmaxf(v, 0.f);
        C[(size_t)(rb + q) * N + col] = (OutT)v;
      }
    }
  }

  if constexpr (STATS) {
    __syncthreads();                      // all frag reads / DMA done; overlay LDS
    float* sRm = (float*)sm;              // [4][256] per-wc row partials
    float* sRs = sRm + 1024;
    float* sCm = sRs + 1024;              // [2][256] per-wr col partials
    float* sCs = sCm + 512;

    // row stats over the wave's 64 cols (reduce ni + lm lanes)
#pragma unroll
    for (int mi = 0; mi < 8; ++mi) {
#pragma unroll
      for (int q = 0; q < 4; ++q) {
        float mloc = fmaxf(fmaxf(acc[mi][0][q], acc[mi][1][q]),
                           fmaxf(acc[mi][2][q], acc[mi][3][q]));
#pragma unroll
        for (int msk = 1; msk < 16; msk <<= 1)
          mloc = fmaxf(mloc, __shfl_xor(mloc, msk));
        float sl = 0.f;
#pragma unroll
        for (int ni = 0; ni < 4; ++ni)
          sl += exp2f((acc[mi][ni][q] - mloc) * L2E);
#pragma unroll
        for (int msk = 1; msk < 16; msk <<= 1)
          sl += __shfl_xor(sl, msk);
        if (lm == 0) {
          int r = wr * 128 + mi * 16 + g * 4 + q;
          sRm[wc * 256 + r] = mloc;
          sRs[wc * 256 + r] = sl;
        }
      }
    }
    // col stats over the wave's 128 rows (reduce mi,q + row-lane groups)
#pragma unroll
    for (int ni = 0; ni < 4; ++ni) {
      float mloc = -3.0e38f;
#pragma unroll
      for (int mi = 0; mi < 8; ++mi)
#pragma unroll
        for (int q = 0; q < 4; ++q)
          mloc = fmaxf(mloc, acc[mi][ni][q]);
      mloc = fmaxf(mloc, __shfl_xor(mloc, 16));
      mloc = fmaxf(mloc, __shfl_xor(mloc, 32));
      float sl = 0.f;
#pragma unroll
      for (int mi = 0; mi < 8; ++mi)
#pragma unroll
        for (int q = 0; q < 4; ++q)
          sl += exp2f((acc[mi][ni][q] - mloc) * L2E);
      sl += __shfl_xor(sl, 16);
      sl += __shfl_xor(sl, 32);
      if (g == 0) {
        int cl = wc * 64 + ni * 16 + lm;
        sCm[wr * 256 + cl] = mloc;
        sCs[wr * 256 + cl] = sl;
      }
    }
    __syncthreads();
    if (t < 256) {
      float M = sRm[t];
#pragma unroll
      for (int j = 1; j < 4; ++j) M = fmaxf(M, sRm[j * 256 + t]);
      float S = 0.f;
#pragma unroll
      for (int j = 0; j < 4; ++j)
        S += sRs[j * 256 + t] * exp2f((sRm[j * 256 + t] - M) * L2E);
      size_t o = ((size_t)bz * 4 + n) * 1024 + m0 + t;
      prm[o] = M;
      prs[o] = S;
    } else {
      int u = t - 256;
      float M = fmaxf(sCm[u], sCm[256 + u]);
      float S = sCs[u] * exp2f((sCm[u] - M) * L2E) +
                sCs[256 + u] * exp2f((sCm[256 + u] - M) * L2E);
      size_t o = ((size_t)bz * 4 + m) * 1024 + n0 + u;
      pcm[o] = M;
      pcs[o] = S;
    }
  }
}

// read e 64x64 tile once; combine partial stats inline (4 tiles now);
// write P (row-softmax) and PT (col-softmax, transposed via LDS)
__global__ __launch_bounds__(256)
void softmax_apply(const float* __restrict__ e,
                   const float* __restrict__ prm, const float* __restrict__ prs,
                   const float* __restrict__ pcm, const float* __restrict__ pcs,
                   _Float16* __restrict__ P, _Float16* __restrict__ PT)
{
  __shared__ _Float16 tl[64][65];
  __shared__ float sRm[64], sRi[64], sCm[64], sCi[64];
  const int bz = blockIdx.z;
  const int r0 = blockIdx.y * 64, c0 = blockIdx.x * 64;
  const size_t bo = (size_t)bz * 1048576;
  const int t = threadIdx.x;

  if (t < 128) {
    const int isCol = t >> 6;
    const int u = t & 63;
    const float* pm = isCol ? pcm : prm;
    const float* ps = isCol ? pcs : prs;
    const int pos = (isCol ? c0 : r0) + u;
    float mj[4], sj[4];
#pragma unroll
    for (int j = 0; j < 4; ++j) {
      size_t o = ((size_t)bz * 4 + j) * 1024 + pos;
      mj[j] = pm[o];
      sj[j] = ps[o];
    }
    float M = -3.0e38f;
#pragma unroll
    for (int j = 0; j < 4; ++j) M = fmaxf(M, mj[j]);
    float S = 0.f;
#pragma unroll
    for (int j = 0; j < 4; ++j) S += sj[j] * exp2f((mj[j] - M) * L2E);
    if (isCol) { sCm[u] = M; sCi[u] = 1.f / S; }
    else       { sRm[u] = M; sRi[u] = 1.f / S; }
  }
  __syncthreads();

#pragma unroll
  for (int p = 0; p < 4; ++p) {
    int idx = p * 256 + t;
    int row = idx >> 4, col4 = (idx & 15) * 4;
    float4 v = *(const float4*)(e + bo + (size_t)(r0 + row) * 1024 + c0 + col4);
    float vv[4] = {v.x, v.y, v.z, v.w};
    const float mrow = sRm[row];
    const float irow = sRi[row];
    half4v op;
#pragma unroll
    for (int j = 0; j < 4; ++j) {
      op[j] = (_Float16)(exp2f((vv[j] - mrow) * L2E) * irow);
      tl[col4 + j][row] = (_Float16)(exp2f((vv[j] - sCm[col4 + j]) * L2E) * sCi[col4 + j]);
    }
    *(half4v*)(P + bo + (size_t)(r0 + row) * 1024 + c0 + col4) = op;
  }
  __syncthreads();
#pragma unroll
  for (int p = 0; p < 4; ++p) {
    int idx = p * 256 + t;
    int trow = idx >> 4, tcol4 = (idx & 15) * 4;
    half4v ov;
#pragma unroll
    for (int j = 0; j < 4; ++j) ov[j] = tl[trow][tcol4 + j];
    *(half4v*)(PT + bo + (size_t)(c0 + trow) * 1024 + r0 + tcol4) = ov;
  }
}

// fp32 (R,C) -> f16 (C,R). DUAL via z >= nb.
__global__ __launch_bounds__(256)
void transpose_cvt(const float* __restrict__ in1, _Float16* __restrict__ out1,
                   const float* __restrict__ in2, _Float16* __restrict__ out2,
                   int R, int C, int nb)
{
  __shared__ float tl[32][33];
  int z = blockIdx.z;
  const float* in = in1;
  _Float16* out = out1;
  if (z >= nb) { z -= nb; in = in2; out = out2; }
  const size_t bo = (size_t)z * R * C;
  int x = blockIdx.x * 32 + threadIdx.x;
  int y0 = blockIdx.y * 32;
  for (int i = threadIdx.y; i < 32; i += 8)
    tl[i][threadIdx.x] = in[bo + (size_t)(y0 + i) * C + x];
  __syncthreads();
  int xo = y0 + threadIdx.x;
  int c0 = blockIdx.x * 32;
  for (int i = threadIdx.y; i < 32; i += 8)
    out[bo + (size_t)(c0 + i) * R + xo] = (_Float16)tl[threadIdx.x][i];
}

__global__ __launch_bounds__(256)
void cvt_f16_2(const float* __restrict__ inA, const float* __restrict__ inB,
               _Float16* __restrict__ oA, _Float16* __restrict__ oB, int n4)
{
  int i = blockIdx.x * 256 + threadIdx.x;
  const float* in = inA;
  _Float16* out = oA;
  if (i >= n4) { i -= n4; in = inB; out = oB; }
  float4 v = ((const float4*)in)[i];
  half4v o;
  o[0] = (_Float16)v.x; o[1] = (_Float16)v.y; o[2] = (_Float16)v.z; o[3] = (_Float16)v.w;
  ((half4v*)out)[i] = o;
}

extern "C" void kernel_launch(void* const* d_in, const int* in_sizes, int n_in,
                              void* d_out, int out_size, void* d_ws, size_t ws_size,
                              hipStream_t stream)
{
  const float* A  = (const float*)d_in[0];
  const float* B  = (const float*)d_in[1];
  const float* W1 = (const float*)d_in[2];
  const float* b1 = (const float*)d_in[3];
  const float* W2 = (const float*)d_in[4];
  const float* b2 = (const float*)d_in[5];
  float* out = (float*)d_out;

  char* ws = (char*)d_ws;
  _Float16* Af  = (_Float16*)(ws + 0);           // X = Af||Bf = (32768,768)
  _Float16* Bf  = (_Float16*)(ws + 25165824);
  _Float16* W1t = (_Float16*)(ws + 50331648);
  _Float16* W2t = (_Float16*)(ws + 51904512);
  // partials overwrite W1t/W2t (dead after gemm2; e-gemm runs later)
  float*    prm = (float*)   (ws + 50331648);
  float*    prs = (float*)   (ws + 50331648 + 524288);
  float*    pcm = (float*)   (ws + 50331648 + 1048576);
  float*    pcs = (float*)   (ws + 50331648 + 1572864);
  _Float16* fAB = (_Float16*)(ws + 54001664);    // (32768,1024)
  _Float16* P   = (_Float16*)(ws + 54001664);    // alias fAB (dead after e-gemm)
  _Float16* PT  = (_Float16*)(ws + 87556096);
  _Float16* h   = (_Float16*)(ws + 121110528);   // (32768,1024)
  float*    e   = (float*)   (ws + 121110528);   // alias h (dead after gemm2)
  _Float16* fA = fAB;
  _Float16* fB = fAB + 16777216;
  _Float16* At = Af;
  _Float16* Bt = Bf;

  dim3 blk(256);
  dim3 blk5(512);
  dim3 tblk(32, 8);

  cvt_f16_2<<<24576, blk, 0, stream>>>(A, B, Af, Bf, 3145728);
  transpose_cvt<<<dim3(32, 24, 1), tblk, 0, stream>>>(W1, W1t, nullptr, nullptr, 768, 1024, 1);
  transpose_cvt<<<dim3(32, 32, 1), tblk, 0, stream>>>(W2, W2t, nullptr, nullptr, 1024, 1024, 1);

  // h = relu([Af;Bf] @ W1 + b1)  (32768x1024), 256x256 tiles: gm=128 gn=4
  gemm_k<768, true, false, _Float16><<<512, blk5, 0, stream>>>(
      Af, W1t, b1, h, 1024, 0, 0, 0, 128, 4, 1,
      nullptr, nullptr, nullptr, nullptr, nullptr, nullptr, nullptr, 0);
  // At/Bt (f16 (768,1024) per batch) — Af/Bf dead after gemm1
  transpose_cvt<<<dim3(24, 32, 32), tblk, 0, stream>>>(A, At, B, Bt, 1024, 768, 16);
  // fAB = relu(h @ W2 + b2)
  gemm_k<1024, true, false, _Float16><<<512, blk5, 0, stream>>>(
      h, W2t, b2, fAB, 1024, 0, 0, 0, 128, 4, 1,
      nullptr, nullptr, nullptr, nullptr, nullptr, nullptr, nullptr, 0);

  // e = fA @ fB^T (batched fp32) + softmax partials: gm=4 gn=4 gz=16
  gemm_k<1024, false, true, float><<<256, blk5, 0, stream>>>(
      fA, fB, nullptr, e, 1024, 1048576L, 1048576L, 1048576L, 4, 4, 16,
      prm, prs, pcm, pcs, nullptr, nullptr, nullptr, 0);

  softmax_apply<<<dim3(16, 16, 16), blk, 0, stream>>>(e, prm, prs, pcm, pcs, P, PT);

  // beta = P @ Bt -> out[0:12582912]; alpha = PT @ At -> out[12582912:]
  // merged launch: gm=4 gn=3 gz=16 per half, shalf = 24
  gemm_k<1024, false, false, float><<<384, blk5, 0, stream>>>(
      P, Bt, nullptr, out, 768, 1048576L, 786432L, 786432L, 4, 3, 16,
      nullptr, nullptr, nullptr, nullptr, PT, At, out + 12582912, 24);
}

// Round 2
// 506.434 us; speedup vs baseline: 1.0167x; 1.0048x over previous
//
#include <hip/hip_runtime.h>
#include <cstdint>

// R7: fine-grained 2-phase-per-slot schedule (T3) on the BK=32 4-slot ring.
// Per slot: phase A {8 ds_read (A m0-3, B n0-3) | stage A-half of s+3 |
// barrier | setprio | 16 MFMA | barrier}, phase B {4 ds_read (A m4-7) |
// stage B-half | vmcnt(8) | barrier | 16 MFMA | barrier}. vmcnt(8)+barrier =
// cross-wave landing proof for slot s+1 (each wave's newest 8 loads are
// slots s+2,s+3; everything older is globally landed after the barrier).
// Write hazard: stage for s+3 hits ring[(s-1)&3], whose reads completed
// before slot s's barriers (reads consumed by MFMAs before closing barrier).
// Tail peels vmcnt 8 -> 4 -> 0 -> 0. Barrier rate = m201's (16 per K=128).

#define L2E 1.4426950408889634f

typedef _Float16 half8 __attribute__((ext_vector_type(8)));
typedef _Float16 half4v __attribute__((ext_vector_type(4)));
typedef float f32x4 __attribute__((ext_vector_type(4)));

__device__ __forceinline__ void gl_lds16(const void* g, void* l) {
  __builtin_amdgcn_global_load_lds(
      (const __attribute__((address_space(1))) unsigned int*)g,
      (__attribute__((address_space(3))) unsigned int*)l, 16, 0, 0);
}

// C(M,N) = op( X(M,K) @ Y(N,K)^T + bias ), op = relu if BIASRELU.
// 1D grid + XCD swizzle (id&7 -> XCD). shalf>0: merged two-gemm launch.
// STATS: emit row/col softmax partials (gn=4 layout).
template<int K, bool BIASRELU, bool STATS, typename OutT>
__global__ __launch_bounds__(512, 2)
void gemm_k(const _Float16* __restrict__ X, const _Float16* __restrict__ Y,
            const float* __restrict__ bias, OutT* __restrict__ C, int N,
            long xbs, long ybs, long cbs, int gm, int gn, int gz,
            float* __restrict__ prm, float* __restrict__ prs,
            float* __restrict__ pcm, float* __restrict__ pcs,
            const _Float16* __restrict__ X2, const _Float16* __restrict__ Y2,
            OutT* __restrict__ C2, int shalf)
{
  constexpr int NS = K / 32;                 // BK=32 slots
  __shared__ __align__(16) _Float16 sm[65536];  // 4 slots x (8192 A + 8192 B)
  const int t = threadIdx.x;
  const int lane = t & 63, w = t >> 6;       // 8 waves
  const int wr = w >> 2, wc = w & 3;         // 2 x 4 wave grid
  const int lm = lane & 15, g = lane >> 4;

  // block decode
  const int id = blockIdx.x;
  const int c = id & 7;
  int s0 = id >> 3;
  if (shalf && s0 >= shalf) { s0 -= shalf; X = X2; Y = Y2; C = C2; }
  int m, n, bz;
  if (gz == 1) {
    int q = s0 / gn;
    n = s0 - q * gn;
    m = c * (gm >> 3) + q;
    bz = 0;
  } else {
    int tpb = gm * gn;
    int bq = s0 / tpb;
    bz = c * (gz >> 3) + bq;
    int r = s0 - bq * tpb;
    m = r / gn;
    n = r - m * gn;
  }
  const int m0 = m * 256, n0 = n * 256;

  X += (size_t)bz * xbs;
  Y += (size_t)bz * ybs;
  C += (size_t)bz * cbs;

  // Staging descriptors. LDS 16B chunk ci = j*512 + t (linear in lane order,
  // as global_load_lds requires). Inverse swizzle to find the global source:
  // phys (lr, p) -> logical chunk cc = p ^ (lr&7); row r = 2*lr + (cc>>2);
  // k-chunk = cc&3.
  const _Float16* ag[2]; const _Float16* bg[2];
  _Float16* al[2]; _Float16* bl[2];
#pragma unroll
  for (int j = 0; j < 2; ++j) {
    int ci = j * 512 + t;
    int lr = ci >> 3, p = ci & 7;
    int cc = p ^ (lr & 7);
    int r = lr * 2 + (cc >> 2);
    int kb = (cc & 3) * 8;
    ag[j] = X + (size_t)(m0 + r) * K + kb;
    bg[j] = Y + (size_t)(n0 + r) * K + kb;
    al[j] = sm + ci * 8;
    bl[j] = sm + 8192 + ci * 8;
  }

  // Fragment LDS offsets (f16 units): logical row r, k-chunk g ->
  // lr = r>>1, chunk = ((r&1)*4 + g) ^ (lr&7).
  int aoff[8], boff[4];
#pragma unroll
  for (int mi = 0; mi < 8; ++mi) {
    int r = wr * 128 + mi * 16 + lm;
    int lr = r >> 1;
    aoff[mi] = lr * 64 + ((((lm & 1) << 2) + g) ^ (lr & 7)) * 8;
  }
#pragma unroll
  for (int ni = 0; ni < 4; ++ni) {
    int r = wc * 64 + ni * 16 + lm;
    int lr = r >> 1;
    boff[ni] = lr * 64 + ((((lm & 1) << 2) + g) ^ (lr & 7)) * 8;
  }

  f32x4 acc[8][4] = {};

#define STAGE_(ss) { \
    const int sb_ = ((ss) & 3) * 16384; \
    const int kt_ = (ss) * 32; \
    gl_lds16(ag[0] + kt_, al[0] + sb_); \
    gl_lds16(ag[1] + kt_, al[1] + sb_); \
    gl_lds16(bg[0] + kt_, bl[0] + sb_); \
    gl_lds16(bg[1] + kt_, bl[1] + sb_); }

#define SLOT_(ss, VM) { \
    const _Float16* ab_ = sm + ((ss) & 3) * 16384; \
    const _Float16* bb_ = ab_ + 8192; \
    const int sb_ = (((ss) + 3) & 3) * 16384; \
    const int kt_ = ((ss) + 3) * 32; \
    const bool st_ = (ss) + 3 < NS; \
    half8 afA[4], bf[4], afB[4]; \
    _Pragma("unroll") \
    for (int mi = 0; mi < 4; ++mi) afA[mi] = *(const half8*)(ab_ + aoff[mi]); \
    _Pragma("unroll") \
    for (int ni = 0; ni < 4; ++ni) bf[ni] = *(const half8*)(bb_ + boff[ni]); \
    if (st_) { gl_lds16(ag[0] + kt_, al[0] + sb_); \
               gl_lds16(ag[1] + kt_, al[1] + sb_); } \
    __builtin_amdgcn_s_barrier(); \
    __builtin_amdgcn_s_setprio(1); \
    _Pragma("unroll") \
    for (int mi = 0; mi < 4; ++mi) \
      _Pragma("unroll") \
      for (int ni = 0; ni < 4; ++ni) \
        acc[mi][ni] = __builtin_amdgcn_mfma_f32_16x16x32_f16(afA[mi], bf[ni], acc[mi][ni], 0, 0, 0); \
    __builtin_amdgcn_s_setprio(0); \
    __builtin_amdgcn_s_barrier(); \
    _Pragma("unroll") \
    for (int mi = 0; mi < 4; ++mi) afB[mi] = *(const half8*)(ab_ + aoff[4 + mi]); \
    if (st_) { gl_lds16(bg[0] + kt_, bl[0] + sb_); \
               gl_lds16(bg[1] + kt_, bl[1] + sb_); } \
    asm volatile("s_waitcnt vmcnt(" #VM ")" ::: "memory"); \
    __builtin_amdgcn_s_barrier(); \
    __builtin_amdgcn_s_setprio(1); \
    _Pragma("unroll") \
    for (int mi = 0; mi < 4; ++mi) \
      _Pragma("unroll") \
      for (int ni = 0; ni < 4; ++ni) \
        acc[4 + mi][ni] = __builtin_amdgcn_mfma_f32_16x16x32_f16(afB[mi], bf[ni], acc[4 + mi][ni], 0, 0, 0); \
    __builtin_amdgcn_s_setprio(0); \
    __builtin_amdgcn_s_barrier(); }

  STAGE_(0); STAGE_(1); STAGE_(2);
  asm volatile("s_waitcnt vmcnt(8)" ::: "memory");
  __builtin_amdgcn_s_barrier();
  for (int ss = 0; ss < NS - 3; ++ss) SLOT_(ss, 8);
  SLOT_(NS - 3, 4);
  SLOT_(NS - 2, 0);
  SLOT_(NS - 1, 0);
#undef STAGE_
#undef SLOT_

  // epilogue: C/D layout col = lane&15, row = (lane>>4)*4 + q
#pragma unroll
  for (int mi = 0; mi < 8; ++mi) {
    const int rb = m0 + wr * 128 + mi * 16 + g * 4;
#pragma unroll
    for (int ni = 0; ni < 4; ++ni) {
      const int col = n0 + wc * 64 + ni * 16 + lm;
      float bv = 0.f;
      if constexpr (BIASRELU) bv = bias[col];
#pragma unroll
      for (int q = 0; q < 4; ++q) {
        float v = acc[mi][ni][q] + bv;
        if constexpr (BIASRELU) v = fmaxf(v, 0.f);
        C[(size_t)(rb + q) * N + col] = (OutT)v;
      }
    }
  }

  if constexpr (STATS) {
    __syncthreads();                      // all frag reads / DMA done; overlay LDS
    float* sRm = (float*)sm;              // [4][256] per-wc row partials
    float* sRs = sRm + 1024;
    float* sCm = sRs + 1024;              // [2][256] per-wr col partials
    float* sCs = sCm + 512;

    // row stats over the wave's 64 cols (reduce ni + lm lanes)
#pragma unroll
    for (int mi = 0; mi < 8; ++mi) {
#pragma unroll
      for (int q = 0; q < 4; ++q) {
        float mloc = fmaxf(fmaxf(acc[mi][0][q], acc[mi][1][q]),
                           fmaxf(acc[mi][2][q], acc[mi][3][q]));
#pragma unroll
        for (int msk = 1; msk < 16; msk <<= 1)
          mloc = fmaxf(mloc, __shfl_xor(mloc, msk));
        float sl = 0.f;
#pragma unroll
        for (int ni = 0; ni < 4; ++ni)
          sl += exp2f((acc[mi][ni][q] - mloc) * L2E);
#pragma unroll
        for (int msk = 1; msk < 16; msk <<= 1)
          sl += __shfl_xor(sl, msk);
        if (lm == 0) {
          int r = wr * 128 + mi * 16 + g * 4 + q;
          sRm[wc * 256 + r] = mloc;
          sRs[wc * 256 + r] = sl;
        }
      }
    }
    // col stats over the wave's 128 rows (reduce mi,q + row-lane groups)
#pragma unroll
    for (int ni = 0; ni < 4; ++ni) {
      float mloc = -3.0e38f;
#pragma unroll
      for (int mi = 0; mi < 8; ++mi)
#pragma unroll
        for (int q = 0; q < 4; ++q)
          mloc = fmaxf(mloc, acc[mi][ni][q]);
      mloc = fmaxf(mloc, __shfl_xor(mloc, 16));
      mloc = fmaxf(mloc, __shfl_xor(mloc, 32));
      float sl = 0.f;
#pragma unroll
      for (int mi = 0; mi < 8; ++mi)
#pragma unroll
        for (int q = 0; q < 4; ++q)
          sl += exp2f((acc[mi][ni][q] - mloc) * L2E);
      sl += __shfl_xor(sl, 16);
      sl += __shfl_xor(sl, 32);
      if (g == 0) {
        int cl = wc * 64 + ni * 16 + lm;
        sCm[wr * 256 + cl] = mloc;
        sCs[wr * 256 + cl] = sl;
      }
    }
    __syncthreads();
    if (t < 256) {
      float M = sRm[t];
#pragma unroll
      for (int j = 1; j < 4; ++j) M = fmaxf(M, sRm[j * 256 + t]);
      float S = 0.f;
#pragma unroll
      for (int j = 0; j < 4; ++j)
        S += sRs[j * 256 + t] * exp2f((sRm[j * 256 + t] - M) * L2E);
      size_t o = ((size_t)bz * 4 + n) * 1024 + m0 + t;
      prm[o] = M;
      prs[o] = S;
    } else {
      int u = t - 256;
      float M = fmaxf(sCm[u], sCm[256 + u]);
      float S = sCs[u] * exp2f((sCm[u] - M) * L2E) +
                sCs[256 + u] * exp2f((sCm[256 + u] - M) * L2E);
      size_t o = ((size_t)bz * 4 + m) * 1024 + n0 + u;
      pcm[o] = M;
      pcs[o] = S;
    }
  }
}

// read e 64x64 tile once; combine partial stats inline (4 tiles);
// write P (row-softmax) and PT (col-softmax, transposed via LDS)
__global__ __launch_bounds__(256)
void softmax_apply(const float* __restrict__ e,
                   const float* __restrict__ prm, const float* __restrict__ prs,
                   const float* __restrict__ pcm, const float* __restrict__ pcs,
                   _Float16* __restrict__ P, _Float16* __restrict__ PT)
{
  __shared__ _Float16 tl[64][65];
  __shared__ float sRm[64], sRi[64], sCm[64], sCi[64];
  const int bz = blockIdx.z;
  const int r0 = blockIdx.y * 64, c0 = blockIdx.x * 64;
  const size_t bo = (size_t)bz * 1048576;
  const int t = threadIdx.x;

  if (t < 128) {
    const int isCol = t >> 6;
    const int u = t & 63;
    const float* pm = isCol ? pcm : prm;
    const float* ps = isCol ? pcs : prs;
    const int pos = (isCol ? c0 : r0) + u;
    float mj[4], sj[4];
#pragma unroll
    for (int j = 0; j < 4; ++j) {
      size_t o = ((size_t)bz * 4 + j) * 1024 + pos;
      mj[j] = pm[o];
      sj[j] = ps[o];
    }
    float M = -3.0e38f;
#pragma unroll
    for (int j = 0; j < 4; ++j) M = fmaxf(M, mj[j]);
    float S = 0.f;
#pragma unroll
    for (int j = 0; j < 4; ++j) S += sj[j] * exp2f((mj[j] - M) * L2E);
    if (isCol) { sCm[u] = M; sCi[u] = 1.f / S; }
    else       { sRm[u] = M; sRi[u] = 1.f / S; }
  }
  __syncthreads();

#pragma unroll
  for (int p = 0; p < 4; ++p) {
    int idx = p * 256 + t;
    int row = idx >> 4, col4 = (idx & 15) * 4;
    float4 v = *(const float4*)(e + bo + (size_t)(r0 + row) * 1024 + c0 + col4);
    float vv[4] = {v.x, v.y, v.z, v.w};
    const float mrow = sRm[row];
    const float irow = sRi[row];
    half4v op;
#pragma unroll
    for (int j = 0; j < 4; ++j) {
      op[j] = (_Float16)(exp2f((vv[j] - mrow) * L2E) * irow);
      tl[col4 + j][row] = (_Float16)(exp2f((vv[j] - sCm[col4 + j]) * L2E) * sCi[col4 + j]);
    }
    *(half4v*)(P + bo + (size_t)(r0 + row) * 1024 + c0 + col4) = op;
  }
  __syncthreads();
#pragma unroll
  for (int p = 0; p < 4; ++p) {
    int idx = p * 256 + t;
    int trow = idx >> 4, tcol4 = (idx & 15) * 4;
    half4v ov;
#pragma unroll
    for (int j = 0; j < 4; ++j) ov[j] = tl[trow][tcol4 + j];
    *(half4v*)(PT + bo + (size_t)(c0 + trow) * 1024 + r0 + tcol4) = ov;
  }
}

// fp32 (R,C) -> f16 (C,R). DUAL via z >= nb.
__global__ __launch_bounds__(256)
void transpose_cvt(const float* __restrict__ in1, _Float16* __restrict__ out1,
                   const float* __restrict__ in2, _Float16* __restrict__ out2,
                   int R, int C, int nb)
{
  __shared__ float tl[32][33];
  int z = blockIdx.z;
  const float* in = in1;
  _Float16* out = out1;
  if (z >= nb) { z -= nb; in = in2; out = out2; }
  const size_t bo = (size_t)z * R * C;
  int x = blockIdx.x * 32 + threadIdx.x;
  int y0 = blockIdx.y * 32;
  for (int i = threadIdx.y; i < 32; i += 8)
    tl[i][threadIdx.x] = in[bo + (size_t)(y0 + i) * C + x];
  __syncthreads();
  int xo = y0 + threadIdx.x;
  int c0 = blockIdx.x * 32;
  for (int i = threadIdx.y; i < 32; i += 8)
    out[bo + (size_t)(c0 + i) * R + xo] = (_Float16)tl[threadIdx.x][i];
}

__global__ __launch_bounds__(256)
void cvt_f16_2(const float* __restrict__ inA, const float* __restrict__ inB,
               _Float16* __restrict__ oA, _Float16* __restrict__ oB, int n4)
{
  int i = blockIdx.x * 256 + threadIdx.x;
  const float* in = inA;
  _Float16* out = oA;
  if (i >= n4) { i -= n4; in = inB; out = oB; }
  float4 v = ((const float4*)in)[i];
  half4v o;
  o[0] = (_Float16)v.x; o[1] = (_Float16)v.y; o[2] = (_Float16)v.z; o[3] = (_Float16)v.w;
  ((half4v*)out)[i] = o;
}

extern "C" void kernel_launch(void* const* d_in, const int* in_sizes, int n_in,
                              void* d_out, int out_size, void* d_ws, size_t ws_size,
                              hipStream_t stream)
{
  const float* A  = (const float*)d_in[0];
  const float* B  = (const float*)d_in[1];
  const float* W1 = (const float*)d_in[2];
  const float* b1 = (const float*)d_in[3];
  const float* W2 = (const float*)d_in[4];
  const float* b2 = (const float*)d_in[5];
  float* out = (float*)d_out;

  char* ws = (char*)d_ws;
  _Float16* Af  = (_Float16*)(ws + 0);           // X = Af||Bf = (32768,768)
  _Float16* Bf  = (_Float16*)(ws + 25165824);
  _Float16* W1t = (_Float16*)(ws + 50331648);
  _Float16* W2t = (_Float16*)(ws + 51904512);
  // partials overwrite W1t/W2t (dead after gemm2; e-gemm runs later)
  float*    prm = (float*)   (ws + 50331648);
  float*    prs = (float*)   (ws + 50331648 + 524288);
  float*    pcm = (float*)   (ws + 50331648 + 1048576);
  float*    pcs = (float*)   (ws + 50331648 + 1572864);
  _Float16* fAB = (_Float16*)(ws + 54001664);    // (32768,1024)
  _Float16* P   = (_Float16*)(ws + 54001664);    // alias fAB (dead after e-gemm)
  _Float16* PT  = (_Float16*)(ws + 87556096);
  _Float16* h   = (_Float16*)(ws + 121110528);   // (32768,1024)
  float*    e   = (float*)   (ws + 121110528);   // alias h (dead after gemm2)
  _Float16* fA = fAB;
  _Float16* fB = fAB + 16777216;
  _Float16* At = Af;
  _Float16* Bt = Bf;

  dim3 blk(256);
  dim3 blk5(512);
  dim3 tblk(32, 8);

  cvt_f16_2<<<24576, blk, 0, stream>>>(A, B, Af, Bf, 3145728);
  transpose_cvt<<<dim3(32, 24, 1), tblk, 0, stream>>>(W1, W1t, nullptr, nullptr, 768, 1024, 1);
  transpose_cvt<<<dim3(32, 32, 1), tblk, 0, stream>>>(W2, W2t, nullptr, nullptr, 1024, 1024, 1);

  // h = relu([Af;Bf] @ W1 + b1)  (32768x1024), 256x256 tiles: gm=128 gn=4
  gemm_k<768, true, false, _Float16><<<512, blk5, 0, stream>>>(
      Af, W1t, b1, h, 1024, 0, 0, 0, 128, 4, 1,
      nullptr, nullptr, nullptr, nullptr, nullptr, nullptr, nullptr, 0);
  // At/Bt (f16 (768,1024) per batch) — Af/Bf dead after gemm1
  transpose_cvt<<<dim3(24, 32, 32), tblk, 0, stream>>>(A, At, B, Bt, 1024, 768, 16);
  // fAB = relu(h @ W2 + b2)
  gemm_k<1024, true, false, _Float16><<<512, blk5, 0, stream>>>(
      h, W2t, b2, fAB, 1024, 0, 0, 0, 128, 4, 1,
      nullptr, nullptr, nullptr, nullptr, nullptr, nullptr, nullptr, 0);

  // e = fA @ fB^T (batched fp32) + softmax partials: gm=4 gn=4 gz=16
  gemm_k<1024, false, true, float><<<256, blk5, 0, stream>>>(
      fA, fB, nullptr, e, 1024, 1048576L, 1048576L, 1048576L, 4, 4, 16,
      prm, prs, pcm, pcs, nullptr, nullptr, nullptr, 0);

  softmax_apply<<<dim3(16, 16, 16), blk, 0, stream>>>(e, prm, prs, pcm, pcs, P, PT);

  // beta = P @ Bt -> out[0:12582912]; alpha = PT @ At -> out[12582912:]
  // merged launch: gm=4 gn=3 gz=16 per half, shalf = 24
  gemm_k<1024, false, false, float><<<384, blk5, 0, stream>>>(
      P, Bt, nullptr, out, 768, 1048576L, 786432L, 786432L, 4, 3, 16,
      nullptr, nullptr, nullptr, nullptr, PT, At, out + 12582912, 24);
}